// Round 1
// baseline (1192.345 us; speedup 1.0000x reference)
//
#include <hip/hip_runtime.h>
#include <math.h>

// Problem constants
// x: (512, 300) f32; pad to 304 = 16*19. Positions: 19*19 = 361.
// t[b,h,w,ch], ch = i1*32 + j1*2 + c; u = xp[j1*19+w], v = xp[i1*19+h];
// c==0: u-v ; c==1: (u-v)/(u+v+1e-5)
// h1 = leaky(t @ w1^T + b1)   (256)
// h2 = leaky(h1 @ w2^T + b2)  (128)
// m3 = relu(h2 @ w3^T + b3)   (64)
// m4 = relu(m3 @ w4^T + b4)   (4)  -> softmax over 361 positions per (q,b)
// out[b, q*32+d] = sum_pos h2[b,pos,q*32+d] * softmax_q[b,pos]

// ws layout (floats): w1t[k*256+o] @0 (131072), w2t[k*128+o] @131072 (32768),
// w3t[k*64+o] @163840 (8192), w4t[k*4+o] @172032 (256). total 172288.

__global__ void transpose_w(const float* __restrict__ w1, const float* __restrict__ w2,
                            const float* __restrict__ w3, const float* __restrict__ w4,
                            float* __restrict__ ws) {
    int i = blockIdx.x * 256 + threadIdx.x;
    if (i < 131072) {
        int k = i >> 8, o = i & 255;
        ws[i] = w1[o * 512 + k];
    } else if (i < 163840) {
        int j = i - 131072; int k = j >> 7, o = j & 127;
        ws[i] = w2[o * 256 + k];
    } else if (i < 172032) {
        int j = i - 163840; int k = j >> 6, o = j & 63;
        ws[i] = w3[o * 128 + k];
    } else if (i < 172288) {
        int j = i - 172032; int k = j >> 2, o = j & 3;
        ws[i] = w4[o * 64 + k];
    }
}

// LDS float offsets:
//   xp : [0, 308)            padded input row (304 used)
//   ts : [308, 308+8192)     t tile   [512][16]
//   h1s: [8500, 8500+4096)   h1 tile  [256][16]
//   h2s: [12596, 12596+2048) h2 tile  [128][16]
//   m3s: alias ts+0   [64][16]
//   lgs: alias ts+1024 [4][16]
// total 14644 floats = 58576 B -> 2 blocks/CU.

template <bool TR>
__global__ __launch_bounds__(256, 2) void fused_kernel(
    const float* __restrict__ x,
    const float* __restrict__ w1, const float* __restrict__ b1,
    const float* __restrict__ w2, const float* __restrict__ b2,
    const float* __restrict__ w3, const float* __restrict__ b3,
    const float* __restrict__ w4, const float* __restrict__ b4,
    float* __restrict__ out)
{
    __shared__ float sm[14644];
    float* const xp  = sm;
    float* const ts  = sm + 308;
    float* const h1s = sm + 8500;
    float* const h2s = sm + 12596;
    float* const m3s = ts;          // reused after layer1 finishes reading ts
    float* const lgs = ts + 1024;

    const int tid = threadIdx.x;
    const int b   = blockIdx.x;

    // stage padded input row
    for (int j = tid; j < 308; j += 256) {
        float v = 0.f;
        const int src = j - 2;
        if (src >= 0 && src < 300) v = x[b * 300 + src];
        xp[j] = v;
    }
    __syncthreads();

    const int q  = tid >> 5;   // head for online-softmax state (tid < 128)
    const int dd = tid & 31;
    float M = -1e30f, S = 0.f, A = 0.f;

    for (int tile = 0; tile < 23; ++tile) {
        const int pos0 = tile * 16;

        // ---- build t tile: thread handles p = tid&15, kk = (tid>>4) + 16*i ----
        {
            const int p    = tid & 15;
            const int kk0  = tid >> 4;
            const int pos  = pos0 + p;
            const bool valid = (pos < 361);
            const int hh = valid ? (pos / 19) : 0;
            const int ww = valid ? (pos - hh * 19) : 0;
            #pragma unroll
            for (int i = 0; i < 16; ++i) {
                const int kk = kk0 + (i << 4);
                const int i1 = kk >> 4, j1 = kk & 15;
                float di = 0.f, ndi = 0.f;
                if (valid) {
                    const float u = xp[j1 * 19 + ww];
                    const float v = xp[i1 * 19 + hh];
                    di  = u - v;
                    ndi = di / (u + v + 1e-5f);
                }
                ts[(kk << 5) + p]      = di;
                ts[(kk << 5) + 16 + p] = ndi;
            }
        }
        __syncthreads();

        // ---- layer 1: 256 outputs, each thread = one output, 16 positions ----
        {
            const int o = tid;
            float acc[16];
            const float bias = b1[o];
            #pragma unroll
            for (int p = 0; p < 16; ++p) acc[p] = bias;
            #pragma unroll 4
            for (int k = 0; k < 512; ++k) {
                const float wv = TR ? w1[(k << 8) + o] : w1[o * 512 + k];
                const float4 t0 = *reinterpret_cast<const float4*>(&ts[(k << 4)]);
                const float4 t1 = *reinterpret_cast<const float4*>(&ts[(k << 4) + 4]);
                const float4 t2 = *reinterpret_cast<const float4*>(&ts[(k << 4) + 8]);
                const float4 t3 = *reinterpret_cast<const float4*>(&ts[(k << 4) + 12]);
                acc[0]  += wv * t0.x; acc[1]  += wv * t0.y; acc[2]  += wv * t0.z; acc[3]  += wv * t0.w;
                acc[4]  += wv * t1.x; acc[5]  += wv * t1.y; acc[6]  += wv * t1.z; acc[7]  += wv * t1.w;
                acc[8]  += wv * t2.x; acc[9]  += wv * t2.y; acc[10] += wv * t2.z; acc[11] += wv * t2.w;
                acc[12] += wv * t3.x; acc[13] += wv * t3.y; acc[14] += wv * t3.z; acc[15] += wv * t3.w;
            }
            #pragma unroll
            for (int p = 0; p < 16; ++p) {
                float v = acc[p];
                v = (v >= 0.f) ? v : 0.01f * v;
                h1s[(o << 4) + p] = v;
            }
        }
        __syncthreads();

        // ---- layer 2: 128 outputs x 2 position-halves ----
        {
            const int o2    = tid & 127;
            const int pbase = (tid >> 7) << 3;   // 0 or 8
            float acc2[8];
            const float bias = b2[o2];
            #pragma unroll
            for (int j = 0; j < 8; ++j) acc2[j] = bias;
            #pragma unroll 4
            for (int k = 0; k < 256; ++k) {
                const float wv = TR ? w2[(k << 7) + o2] : w2[o2 * 256 + k];
                const float4 a0 = *reinterpret_cast<const float4*>(&h1s[(k << 4) + pbase]);
                const float4 a1 = *reinterpret_cast<const float4*>(&h1s[(k << 4) + pbase + 4]);
                acc2[0] += wv * a0.x; acc2[1] += wv * a0.y; acc2[2] += wv * a0.z; acc2[3] += wv * a0.w;
                acc2[4] += wv * a1.x; acc2[5] += wv * a1.y; acc2[6] += wv * a1.z; acc2[7] += wv * a1.w;
            }
            #pragma unroll
            for (int j = 0; j < 8; ++j) {
                float v = acc2[j];
                v = (v >= 0.f) ? v : 0.01f * v;
                h2s[(o2 << 4) + pbase + j] = v;
            }
        }
        __syncthreads();

        // ---- layer 3: 64 outputs x 4 position-quarters (writes alias ts) ----
        {
            const int o3    = tid & 63;
            const int pbase = (tid >> 6) << 2;   // 0,4,8,12
            float acc3[4];
            const float bias = b3[o3];
            #pragma unroll
            for (int j = 0; j < 4; ++j) acc3[j] = bias;
            #pragma unroll 4
            for (int k = 0; k < 128; ++k) {
                const float wv = TR ? w3[(k << 6) + o3] : w3[o3 * 128 + k];
                const float4 a0 = *reinterpret_cast<const float4*>(&h2s[(k << 4) + pbase]);
                acc3[0] += wv * a0.x; acc3[1] += wv * a0.y; acc3[2] += wv * a0.z; acc3[3] += wv * a0.w;
            }
            #pragma unroll
            for (int j = 0; j < 4; ++j) {
                m3s[(o3 << 4) + pbase + j] = fmaxf(acc3[j], 0.f);
            }
        }
        __syncthreads();

        // ---- layer 4 + relu + position mask -> logits ----
        if (tid < 64) {
            const int o4 = tid >> 4;
            const int p  = tid & 15;
            float a = b4[o4];
            #pragma unroll 8
            for (int k = 0; k < 64; ++k) {
                const float wv = TR ? w4[(k << 2) + o4] : w4[o4 * 64 + k];
                a += wv * m3s[(k << 4) + p];
            }
            a = fmaxf(a, 0.f);
            if (pos0 + p >= 361) a = -1e30f;
            lgs[(o4 << 4) + p] = a;
        }
        __syncthreads();

        // ---- online softmax update: tid<128 holds (q, dd) accumulator ----
        if (tid < 128) {
            float l[16];
            #pragma unroll
            for (int p = 0; p < 16; ++p) l[p] = lgs[(q << 4) + p];
            float tmax = l[0];
            #pragma unroll
            for (int p = 1; p < 16; ++p) tmax = fmaxf(tmax, l[p]);
            const float newM  = fmaxf(M, tmax);
            const float alpha = __expf(M - newM);
            float ssum = 0.f, asum = 0.f;
            #pragma unroll
            for (int p = 0; p < 16; ++p) {
                const float e = __expf(l[p] - newM);
                ssum += e;
                asum += e * h2s[(((q << 5) + dd) << 4) + p];
            }
            S = S * alpha + ssum;
            A = A * alpha + asum;
            M = newM;
        }
        __syncthreads();   // protect ts/lgs/h2s before next tile overwrites
    }

    if (tid < 128) {
        out[(b << 7) + tid] = A / S;
    }
}

extern "C" void kernel_launch(void* const* d_in, const int* in_sizes, int n_in,
                              void* d_out, int out_size, void* d_ws, size_t ws_size,
                              hipStream_t stream) {
    const float* x  = (const float*)d_in[0];
    const float* w1 = (const float*)d_in[1];
    const float* b1 = (const float*)d_in[2];
    const float* w2 = (const float*)d_in[3];
    const float* b2 = (const float*)d_in[4];
    const float* w3 = (const float*)d_in[5];
    const float* b3 = (const float*)d_in[6];
    const float* w4 = (const float*)d_in[7];
    const float* b4 = (const float*)d_in[8];
    float* out = (float*)d_out;
    float* ws  = (float*)d_ws;

    const bool tr = (ws_size >= 172288u * sizeof(float));
    if (tr) {
        transpose_w<<<673, 256, 0, stream>>>(w1, w2, w3, w4, ws);
        fused_kernel<true><<<512, 256, 0, stream>>>(
            x, ws, b1, ws + 131072, b2, ws + 163840, b3, ws + 172032, b4, out);
    } else {
        fused_kernel<false><<<512, 256, 0, stream>>>(
            x, w1, b1, w2, b2, w3, b3, w4, b4, out);
    }
}

// Round 2
// 190.644 us; speedup vs baseline: 6.2543x; 6.2543x over previous
//
#include <hip/hip_runtime.h>
#include <math.h>

typedef unsigned short ushort_t;
typedef __attribute__((ext_vector_type(8))) short short8;
typedef __attribute__((ext_vector_type(4))) float f32x4;

__device__ inline ushort_t f2bf(float f) {
    unsigned u = __float_as_uint(f);
    return (ushort_t)((u + 0x7FFFu + ((u >> 16) & 1u)) >> 16);
}
__device__ inline float bf2f(ushort_t h) {
    return __uint_as_float(((unsigned)h) << 16);
}
__device__ inline float leaky(float v) { return v >= 0.f ? v : 0.01f * v; }

// ws ushort layout (bf16 MFMA A-fragments, lane-major 16B blocks):
//   L1 @0      : 16 outsub x 16 kstep x 64 lane x 8  = 131072
//   L2 @131072 :  8 outsub x  8 kstep x 64 lane x 8  =  32768
//   L3 @163840 :  4 outsub x  4 kstep x 64 lane x 8  =   8192
//   L4 @172032 :  1 outsub x  2 kstep x 64 lane x 8  =   1024 (rows 4..15 zero)
#define WS_USHORTS 173056

__global__ void pack_weights(const float* __restrict__ w1, const float* __restrict__ w2,
                             const float* __restrict__ w3, const float* __restrict__ w4,
                             ushort_t* __restrict__ ws) {
    int idx = blockIdx.x * 256 + threadIdx.x;
    float val = 0.f;
    if (idx < 131072) {
        int j = idx & 7, u = idx >> 3, lane = u & 63, blk = u >> 6;
        int m = lane & 15, q = lane >> 4;
        int ks = blk & 15, os = blk >> 4;
        val = w1[(os * 16 + m) * 512 + ks * 32 + q * 8 + j];
    } else if (idx < 163840) {
        int l = idx - 131072;
        int j = l & 7, u = l >> 3, lane = u & 63, blk = u >> 6;
        int m = lane & 15, q = lane >> 4;
        int ks = blk & 7, os = blk >> 3;
        val = w2[(os * 16 + m) * 256 + ks * 32 + q * 8 + j];
    } else if (idx < 172032) {
        int l = idx - 163840;
        int j = l & 7, u = l >> 3, lane = u & 63, blk = u >> 6;
        int m = lane & 15, q = lane >> 4;
        int ks = blk & 3, os = blk >> 2;
        val = w3[(os * 16 + m) * 128 + ks * 32 + q * 8 + j];
    } else if (idx < 173056) {
        int l = idx - 172032;
        int j = l & 7, u = l >> 3, lane = u & 63, blk = u >> 6;  // blk = kstep 0..1
        int m = lane & 15, q = lane >> 4;
        val = (m < 4) ? w4[m * 64 + blk * 32 + q * 8 + j] : 0.f;
    }
    ws[idx] = f2bf(val);
}

// LDS (ushort units, all row strides 16B-aligned, stride%32dw==4 -> 2-way=free):
//   ts  @0      [32][520]   t tile bf16
//   h1s @16640  [32][264]
//   h2s @25088  [32][136]
//   m3s @29440  [32][72]
//   xp  @31744  308 f32
//   lgs @32360  [4][32] f32
__global__ __launch_bounds__(256, 2) void fused_mfma(
    const float* __restrict__ x, const ushort_t* __restrict__ ws,
    const float* __restrict__ b1, const float* __restrict__ b2,
    const float* __restrict__ b3, const float* __restrict__ b4,
    float* __restrict__ out)
{
    __shared__ __align__(16) ushort_t sm[32616];
    ushort_t* const ts  = sm;
    ushort_t* const h1s = sm + 16640;
    ushort_t* const h2s = sm + 25088;
    ushort_t* const m3s = sm + 29440;
    float*   const xp   = (float*)(sm + 31744);
    float*   const lgs  = (float*)(sm + 32360);

    const int tid  = threadIdx.x;
    const int b    = blockIdx.x;
    const int wid  = tid >> 6;
    const int lane = tid & 63;
    const int n0   = lane & 15;          // B-operand n (position within subtile)
    const int q8   = (lane >> 4) * 8;    // k-offset within kstep
    const int row0 = (lane >> 4) * 4;    // C-frag row base (output channel)

    for (int jj = tid; jj < 308; jj += 256) {
        float v = 0.f;
        const int src = jj - 2;
        if (src >= 0 && src < 300) v = x[b * 300 + src];
        xp[jj] = v;
    }
    __syncthreads();

    const short8* wf1 = (const short8*)(ws);
    const short8* wf2 = (const short8*)(ws + 131072);
    const short8* wf3 = (const short8*)(ws + 163840);
    const short8* wf4 = (const short8*)(ws + 172032);

    const int q  = tid >> 5;
    const int dd = tid & 31;
    float M = -1e30f, S = 0.f, A = 0.f;
    const f32x4 z4 = {0.f, 0.f, 0.f, 0.f};

    for (int tile = 0; tile < 12; ++tile) {
        const int pos0 = tile * 32;

        // ---- build t tile (bf16 DI/NDI pairs) ----
        {
            const int p   = tid & 31;
            const int jj0 = tid >> 5;          // 0..7
            int posg = pos0 + p; if (posg > 360) posg = 360;
            const int hh = posg / 19;
            const int ww = posg - hh * 19;
            #pragma unroll
            for (int i1 = 0; i1 < 16; ++i1) {
                const float v = xp[i1 * 19 + hh];
                #pragma unroll
                for (int jt = 0; jt < 2; ++jt) {
                    const int j1 = jj0 + jt * 8;
                    const float uu = xp[j1 * 19 + ww];
                    const float di = uu - v;
                    const float nd = di * __builtin_amdgcn_rcpf(uu + v + 1e-5f);
                    const unsigned pk = (unsigned)f2bf(di) | ((unsigned)f2bf(nd) << 16);
                    *(unsigned*)&ts[p * 520 + i1 * 32 + j1 * 2] = pk;
                }
            }
        }
        __syncthreads();

        // ---- layer 1: 256 outs, K=512. wave: 4 outsubs x 2 possubs ----
        {
            f32x4 acc[4][2];
            #pragma unroll
            for (int jo = 0; jo < 4; ++jo) { acc[jo][0] = z4; acc[jo][1] = z4; }
            const int tb0 = n0 * 520 + q8;
            const int tb1 = tb0 + 16 * 520;
            #pragma unroll 4
            for (int ks = 0; ks < 16; ++ks) {
                const short8 bb0 = *(const short8*)&ts[tb0 + ks * 32];
                const short8 bb1 = *(const short8*)&ts[tb1 + ks * 32];
                #pragma unroll
                for (int jo = 0; jo < 4; ++jo) {
                    const short8 a = wf1[((wid * 4 + jo) * 16 + ks) * 64 + lane];
                    acc[jo][0] = __builtin_amdgcn_mfma_f32_16x16x32_bf16(a, bb0, acc[jo][0], 0, 0, 0);
                    acc[jo][1] = __builtin_amdgcn_mfma_f32_16x16x32_bf16(a, bb1, acc[jo][1], 0, 0, 0);
                }
            }
            #pragma unroll
            for (int jo = 0; jo < 4; ++jo) {
                const int out0 = (wid * 4 + jo) * 16 + row0;
                const float g0 = b1[out0], g1 = b1[out0 + 1], g2 = b1[out0 + 2], g3 = b1[out0 + 3];
                #pragma unroll
                for (int ps = 0; ps < 2; ++ps) {
                    const int pos = ps * 16 + n0;
                    const f32x4 a4 = acc[jo][ps];
                    uint2 pk;
                    pk.x = (unsigned)f2bf(leaky(a4.x + g0)) | ((unsigned)f2bf(leaky(a4.y + g1)) << 16);
                    pk.y = (unsigned)f2bf(leaky(a4.z + g2)) | ((unsigned)f2bf(leaky(a4.w + g3)) << 16);
                    *(uint2*)&h1s[pos * 264 + out0] = pk;
                }
            }
        }
        __syncthreads();

        // ---- layer 2: 128 outs, K=256. wave: 2 outsubs x 2 possubs ----
        {
            f32x4 acc[2][2];
            #pragma unroll
            for (int jo = 0; jo < 2; ++jo) { acc[jo][0] = z4; acc[jo][1] = z4; }
            const int hb0 = n0 * 264 + q8;
            const int hb1 = hb0 + 16 * 264;
            #pragma unroll 4
            for (int ks = 0; ks < 8; ++ks) {
                const short8 bb0 = *(const short8*)&h1s[hb0 + ks * 32];
                const short8 bb1 = *(const short8*)&h1s[hb1 + ks * 32];
                #pragma unroll
                for (int jo = 0; jo < 2; ++jo) {
                    const short8 a = wf2[((wid * 2 + jo) * 8 + ks) * 64 + lane];
                    acc[jo][0] = __builtin_amdgcn_mfma_f32_16x16x32_bf16(a, bb0, acc[jo][0], 0, 0, 0);
                    acc[jo][1] = __builtin_amdgcn_mfma_f32_16x16x32_bf16(a, bb1, acc[jo][1], 0, 0, 0);
                }
            }
            #pragma unroll
            for (int jo = 0; jo < 2; ++jo) {
                const int out0 = (wid * 2 + jo) * 16 + row0;
                const float g0 = b2[out0], g1 = b2[out0 + 1], g2 = b2[out0 + 2], g3 = b2[out0 + 3];
                #pragma unroll
                for (int ps = 0; ps < 2; ++ps) {
                    const int pos = ps * 16 + n0;
                    const f32x4 a4 = acc[jo][ps];
                    uint2 pk;
                    pk.x = (unsigned)f2bf(leaky(a4.x + g0)) | ((unsigned)f2bf(leaky(a4.y + g1)) << 16);
                    pk.y = (unsigned)f2bf(leaky(a4.z + g2)) | ((unsigned)f2bf(leaky(a4.w + g3)) << 16);
                    *(uint2*)&h2s[pos * 136 + out0] = pk;
                }
            }
        }
        __syncthreads();

        // ---- layer 3: 64 outs, K=128. wave: 1 outsub x 2 possubs ----
        {
            f32x4 acc[2] = {z4, z4};
            const int hb0 = n0 * 136 + q8;
            const int hb1 = hb0 + 16 * 136;
            #pragma unroll
            for (int ks = 0; ks < 4; ++ks) {
                const short8 bb0 = *(const short8*)&h2s[hb0 + ks * 32];
                const short8 bb1 = *(const short8*)&h2s[hb1 + ks * 32];
                const short8 a = wf3[(wid * 4 + ks) * 64 + lane];
                acc[0] = __builtin_amdgcn_mfma_f32_16x16x32_bf16(a, bb0, acc[0], 0, 0, 0);
                acc[1] = __builtin_amdgcn_mfma_f32_16x16x32_bf16(a, bb1, acc[1], 0, 0, 0);
            }
            const int out0 = wid * 16 + row0;
            const float g0 = b3[out0], g1 = b3[out0 + 1], g2 = b3[out0 + 2], g3 = b3[out0 + 3];
            #pragma unroll
            for (int ps = 0; ps < 2; ++ps) {
                const int pos = ps * 16 + n0;
                const f32x4 a4 = acc[ps];
                uint2 pk;
                pk.x = (unsigned)f2bf(fmaxf(a4.x + g0, 0.f)) | ((unsigned)f2bf(fmaxf(a4.y + g1, 0.f)) << 16);
                pk.y = (unsigned)f2bf(fmaxf(a4.z + g2, 0.f)) | ((unsigned)f2bf(fmaxf(a4.w + g3, 0.f)) << 16);
                *(uint2*)&m3s[pos * 72 + out0] = pk;
            }
        }
        __syncthreads();

        // ---- layer 4: 4 outs, K=64 (wave 0 only) -> masked logits ----
        if (wid == 0) {
            f32x4 acc[2] = {z4, z4};
            const int mb0 = n0 * 72 + q8;
            const int mb1 = mb0 + 16 * 72;
            #pragma unroll
            for (int ks = 0; ks < 2; ++ks) {
                const short8 bb0 = *(const short8*)&m3s[mb0 + ks * 32];
                const short8 bb1 = *(const short8*)&m3s[mb1 + ks * 32];
                const short8 a = wf4[ks * 64 + lane];
                acc[0] = __builtin_amdgcn_mfma_f32_16x16x32_bf16(a, bb0, acc[0], 0, 0, 0);
                acc[1] = __builtin_amdgcn_mfma_f32_16x16x32_bf16(a, bb1, acc[1], 0, 0, 0);
            }
            if (lane < 16) {   // rows 0..3 live in lanes 0..15
                #pragma unroll
                for (int ps = 0; ps < 2; ++ps) {
                    const int pos = ps * 16 + lane;
                    const bool bad = (pos0 + pos) > 360;
                    const f32x4 a4 = acc[ps];
                    lgs[0 * 32 + pos] = bad ? -1e30f : fmaxf(a4.x + b4[0], 0.f);
                    lgs[1 * 32 + pos] = bad ? -1e30f : fmaxf(a4.y + b4[1], 0.f);
                    lgs[2 * 32 + pos] = bad ? -1e30f : fmaxf(a4.z + b4[2], 0.f);
                    lgs[3 * 32 + pos] = bad ? -1e30f : fmaxf(a4.w + b4[3], 0.f);
                }
            }
        }
        __syncthreads();

        // ---- online softmax + weighted h2 accumulation (tid<128: ch=tid) ----
        if (tid < 128) {
            float l[32];
            float tmax = -1e30f;
            #pragma unroll
            for (int p = 0; p < 32; ++p) { l[p] = lgs[q * 32 + p]; tmax = fmaxf(tmax, l[p]); }
            const float newM  = fmaxf(M, tmax);
            const float alpha = __expf(M - newM);
            float ssum = 0.f, asum = 0.f;
            #pragma unroll
            for (int p = 0; p < 32; ++p) {
                const float e = __expf(l[p] - newM);
                ssum += e;
                asum += e * bf2f(h2s[p * 136 + tid]);
            }
            S = S * alpha + ssum;
            A = A * alpha + asum;
            M = newM;
        }
        __syncthreads();
    }

    if (tid < 128) out[(b << 7) + tid] = A / S;
}

// ---------------- f32 scalar fallback (known-correct, ws-free) ----------------
__global__ __launch_bounds__(256, 2) void fallback_fused(
    const float* __restrict__ x,
    const float* __restrict__ w1, const float* __restrict__ b1,
    const float* __restrict__ w2, const float* __restrict__ b2,
    const float* __restrict__ w3, const float* __restrict__ b3,
    const float* __restrict__ w4, const float* __restrict__ b4,
    float* __restrict__ out)
{
    __shared__ float smf[14644];
    float* const xp  = smf;
    float* const ts  = smf + 308;
    float* const h1s = smf + 8500;
    float* const h2s = smf + 12596;
    float* const m3s = ts;
    float* const lgs = ts + 1024;

    const int tid = threadIdx.x;
    const int b   = blockIdx.x;
    for (int j = tid; j < 308; j += 256) {
        float v = 0.f;
        const int src = j - 2;
        if (src >= 0 && src < 300) v = x[b * 300 + src];
        xp[j] = v;
    }
    __syncthreads();
    const int q = tid >> 5, dd = tid & 31;
    float M = -1e30f, S = 0.f, A = 0.f;
    for (int tile = 0; tile < 23; ++tile) {
        const int pos0 = tile * 16;
        {
            const int p = tid & 15, kk0 = tid >> 4;
            const int pos = pos0 + p;
            const bool valid = (pos < 361);
            const int hh = valid ? (pos / 19) : 0;
            const int ww = valid ? (pos - hh * 19) : 0;
            #pragma unroll
            for (int i = 0; i < 16; ++i) {
                const int kk = kk0 + (i << 4);
                const int i1 = kk >> 4, j1 = kk & 15;
                float di = 0.f, ndi = 0.f;
                if (valid) {
                    const float u = xp[j1 * 19 + ww];
                    const float v = xp[i1 * 19 + hh];
                    di = u - v; ndi = di / (u + v + 1e-5f);
                }
                ts[(kk << 5) + p] = di;
                ts[(kk << 5) + 16 + p] = ndi;
            }
        }
        __syncthreads();
        {
            const int o = tid;
            float acc[16];
            const float bias = b1[o];
            #pragma unroll
            for (int p = 0; p < 16; ++p) acc[p] = bias;
            for (int k = 0; k < 512; ++k) {
                const float wv = w1[o * 512 + k];
                #pragma unroll
                for (int p = 0; p < 16; ++p) acc[p] += wv * ts[(k << 4) + p];
            }
            #pragma unroll
            for (int p = 0; p < 16; ++p) h1s[(o << 4) + p] = leaky(acc[p]);
        }
        __syncthreads();
        {
            const int o2 = tid & 127, pb = (tid >> 7) << 3;
            float acc[8];
            const float bias = b2[o2];
            #pragma unroll
            for (int j = 0; j < 8; ++j) acc[j] = bias;
            for (int k = 0; k < 256; ++k) {
                const float wv = w2[o2 * 256 + k];
                #pragma unroll
                for (int j = 0; j < 8; ++j) acc[j] += wv * h1s[(k << 4) + pb + j];
            }
            #pragma unroll
            for (int j = 0; j < 8; ++j) h2s[(o2 << 4) + pb + j] = leaky(acc[j]);
        }
        __syncthreads();
        {
            const int o3 = tid & 63, pb = (tid >> 6) << 2;
            float acc[4];
            const float bias = b3[o3];
            #pragma unroll
            for (int j = 0; j < 4; ++j) acc[j] = bias;
            for (int k = 0; k < 128; ++k) {
                const float wv = w3[o3 * 128 + k];
                #pragma unroll
                for (int j = 0; j < 4; ++j) acc[j] += wv * h2s[(k << 4) + pb + j];
            }
            #pragma unroll
            for (int j = 0; j < 4; ++j) m3s[(o3 << 4) + pb + j] = fmaxf(acc[j], 0.f);
        }
        __syncthreads();
        if (tid < 64) {
            const int o4 = tid >> 4, p = tid & 15;
            float a = b4[o4];
            for (int k = 0; k < 64; ++k) a += w4[o4 * 64 + k] * m3s[(k << 4) + p];
            a = fmaxf(a, 0.f);
            if (pos0 + p >= 361) a = -1e30f;
            lgs[(o4 << 4) + p] = a;
        }
        __syncthreads();
        if (tid < 128) {
            float l[16];
            #pragma unroll
            for (int p = 0; p < 16; ++p) l[p] = lgs[(q << 4) + p];
            float tmax = l[0];
            #pragma unroll
            for (int p = 1; p < 16; ++p) tmax = fmaxf(tmax, l[p]);
            const float newM = fmaxf(M, tmax);
            const float alpha = __expf(M - newM);
            float ssum = 0.f, asum = 0.f;
            #pragma unroll
            for (int p = 0; p < 16; ++p) {
                const float e = __expf(l[p] - newM);
                ssum += e;
                asum += e * h2s[(((q << 5) + dd) << 4) + p];
            }
            S = S * alpha + ssum; A = A * alpha + asum; M = newM;
        }
        __syncthreads();
    }
    if (tid < 128) out[(b << 7) + tid] = A / S;
}

extern "C" void kernel_launch(void* const* d_in, const int* in_sizes, int n_in,
                              void* d_out, int out_size, void* d_ws, size_t ws_size,
                              hipStream_t stream) {
    const float* x  = (const float*)d_in[0];
    const float* w1 = (const float*)d_in[1];
    const float* b1 = (const float*)d_in[2];
    const float* w2 = (const float*)d_in[3];
    const float* b2 = (const float*)d_in[4];
    const float* w3 = (const float*)d_in[5];
    const float* b3 = (const float*)d_in[6];
    const float* w4 = (const float*)d_in[7];
    const float* b4 = (const float*)d_in[8];
    float* out = (float*)d_out;

    if (ws_size >= (size_t)WS_USHORTS * sizeof(ushort_t)) {
        ushort_t* ws = (ushort_t*)d_ws;
        pack_weights<<<676, 256, 0, stream>>>(w1, w2, w3, w4, ws);
        fused_mfma<<<512, 256, 0, stream>>>(x, ws, b1, b2, b3, b4, out);
    } else {
        fallback_fused<<<512, 256, 0, stream>>>(x, w1, b1, w2, b2, w3, b3, w4, b4, out);
    }
}